// Round 3
// baseline (118.882 us; speedup 1.0000x reference)
//
#include <hip/hip_runtime.h>

typedef __bf16 bf16x8 __attribute__((ext_vector_type(8)));
typedef float f32x4 __attribute__((ext_vector_type(4)));
typedef float f32x2 __attribute__((ext_vector_type(2)));

#define G_N 2000
#define K_N 64
#define DEG_INN 8
#define DEG_EXTN 16
#define B_N 1024
#define D 128
#define NT_N 10000

// fp8 scale for P/Q tables (values ~N(0,0.014^2); x256 puts them mid e4m3 range)
#define PQ_SCALE 256.0f
#define PQ_INV   (1.0f / 256.0f)

__device__ __forceinline__ float bflo(unsigned int u) { return __uint_as_float(u << 16); }
__device__ __forceinline__ float bfhi(unsigned int u) { return __uint_as_float(u & 0xffff0000u); }
__device__ __forceinline__ unsigned short f2bf(float f) {
  unsigned int u = __float_as_uint(f);
  u += 0x7fffu + ((u >> 16) & 1u);
  return (unsigned short)(u >> 16);
}
__device__ __forceinline__ unsigned int pack2bf(float lo, float hi) {
  return ((unsigned int)f2bf(hi) << 16) | (unsigned int)f2bf(lo);
}

// expand 16 packed fp8 (uint4) into 16 f32
__device__ __forceinline__ void fp8x16_to_f32(uint4 v, float* o) {
  f32x2 t;
  t = __builtin_amdgcn_cvt_pk_f32_fp8(v.x, false); o[0]  = t[0]; o[1]  = t[1];
  t = __builtin_amdgcn_cvt_pk_f32_fp8(v.x, true);  o[2]  = t[0]; o[3]  = t[1];
  t = __builtin_amdgcn_cvt_pk_f32_fp8(v.y, false); o[4]  = t[0]; o[5]  = t[1];
  t = __builtin_amdgcn_cvt_pk_f32_fp8(v.y, true);  o[6]  = t[0]; o[7]  = t[1];
  t = __builtin_amdgcn_cvt_pk_f32_fp8(v.z, false); o[8]  = t[0]; o[9]  = t[1];
  t = __builtin_amdgcn_cvt_pk_f32_fp8(v.z, true);  o[10] = t[0]; o[11] = t[1];
  t = __builtin_amdgcn_cvt_pk_f32_fp8(v.w, false); o[12] = t[0]; o[13] = t[1];
  t = __builtin_amdgcn_cvt_pk_f32_fp8(v.w, true);  o[14] = t[0]; o[15] = t[1];
}
__device__ __forceinline__ void fp8x16_acc(uint4 v, float* rv) {
  float t[16];
  fp8x16_to_f32(v, t);
  #pragma unroll
  for (int i = 0; i < 16; ++i) rv[i] += t[i];
}

// ---------------- K0: P=impact@W^T, Q=impact@M^T (fp8 e4m3 x256) + transposes
// grid (157,3): y=0 -> P, y=1 -> Q, y=2 (x<64) -> Ut/Vt/W1t bf16 transposes.
// NOTE (R6 post-mortem): fusing y=0/y=1 into one block REGRESSED 134.8->159.1;
// latency/occupancy-bound, keep high block counts + low VGPR.
// NOTE (R10 post-mortem): k1 shfl-slot-reduction + bf16 E regressed.
// NOTE (R11 post-mortem): cooperative k1+k3+k4 fusion REGRESSED 119->594 us.
// grid.sync() at 2000 blocks costs ~250 us/sync on gfx950. Never retry.
// R12 WIN: Ut/Vt/W1t k-interleaved-by-4, k3/k4 read uint4 -> 116.7 us.
// R13 (this round): k1 gathers via uint4 (8 lanes/row) -> 18 instead of 36
// gathered VMEM instrs/thread; same bytes, same math.
constexpr int LD1 = 136;

__global__ __launch_bounds__(256)
void k0_prep(const float* __restrict__ impact,
             const float* __restrict__ Wm, const float* __restrict__ Mm,
             const float* __restrict__ U, const float* __restrict__ V,
             const float* __restrict__ W1,
             unsigned int* __restrict__ P8, unsigned int* __restrict__ Q8,
             unsigned int* __restrict__ Ut, unsigned int* __restrict__ Vt,
             unsigned int* __restrict__ W1t)
{
  __shared__ __align__(16) unsigned short Bs[128 * LD1];
  __shared__ __align__(16) unsigned short As[64 * LD1];

  const int tid = threadIdx.x;

  if (blockIdx.y == 2) {
    if (blockIdx.x >= 64) return;
    const int t = blockIdx.x * 256 + tid;       // [0, 16384)
    if (t < 8192) {                              // Ut/Vt: k = t>>6 in [0,128), jc = t&63
      int k = t >> 6, jc = t & 63;
      // k-interleaved-by-4 layout: uint4 at [(k>>2)*64 + jc] holds k..k+3
      int idx = (k >> 2) * 256 + jc * 4 + (k & 3);
      Ut[idx] = pack2bf(U[(size_t)(2 * jc) * D + k], U[(size_t)(2 * jc + 1) * D + k]);
      Vt[idx] = pack2bf(V[(size_t)(2 * jc) * D + k], V[(size_t)(2 * jc + 1) * D + k]);
    }
    {                                            // W1t: k = t>>6 in [0,256), jc = t&63
      int k = t >> 6, jc = t & 63;
      int idx = (k >> 2) * 256 + jc * 4 + (k & 3);
      W1t[idx] = pack2bf(W1[(size_t)(2 * jc) * 256 + k], W1[(size_t)(2 * jc + 1) * 256 + k]);
    }
    return;
  }

  const int rowbase = blockIdx.x * 64;
  const float* Bsrc = blockIdx.y ? Mm : Wm;
  unsigned int* dst = blockIdx.y ? Q8 : P8;
  const int wave = tid >> 6, lane = tid & 63;

  for (int i = tid; i < 128 * 32; i += 256) {
    int row = i >> 5, c4 = i & 31;
    float4 v = ((const float4*)Bsrc)[row * 32 + c4];
    *(unsigned int*)(Bs + row * LD1 + c4 * 4)     = pack2bf(v.x, v.y);
    *(unsigned int*)(Bs + row * LD1 + c4 * 4 + 2) = pack2bf(v.z, v.w);
  }
  for (int i = tid; i < 64 * 32; i += 256) {
    int r = i >> 5, c4 = i & 31;
    int gr = rowbase + r; if (gr > NT_N - 1) gr = NT_N - 1;
    float4 v = ((const float4*)impact)[(size_t)gr * 32 + c4];
    *(unsigned int*)(As + r * LD1 + c4 * 4)     = pack2bf(v.x, v.y);
    *(unsigned int*)(As + r * LD1 + c4 * 4 + 2) = pack2bf(v.z, v.w);
  }
  __syncthreads();

  f32x4 acc[8];
  #pragma unroll
  for (int n = 0; n < 8; ++n) acc[n] = (f32x4){0.f, 0.f, 0.f, 0.f};
  const int qk   = (lane >> 4) * 8;
  const int arow = wave * 16 + (lane & 15);
  #pragma unroll
  for (int kk = 0; kk < 4; ++kk) {
    bf16x8 af = *(const bf16x8*)(As + arow * LD1 + kk * 32 + qk);
    #pragma unroll
    for (int n = 0; n < 8; ++n) {
      bf16x8 bfr = *(const bf16x8*)(Bs + (n * 16 + (lane & 15)) * LD1 + kk * 32 + qk);
      acc[n] = __builtin_amdgcn_mfma_f32_16x16x32_bf16(af, bfr, acc[n], 0, 0, 0);
    }
  }
  __syncthreads();

  // repack C (col=lane&15, row=(lane>>4)*4+reg) into As as bf16 rows
  const int quad = lane >> 4, c = lane & 15;
  #pragma unroll
  for (int n = 0; n < 8; ++n)
    #pragma unroll
    for (int reg = 0; reg < 4; ++reg)
      As[(wave * 16 + quad * 4 + reg) * LD1 + n * 16 + c] = f2bf(acc[n][reg]);
  __syncthreads();

  // write fp8 e4m3 (x256): row = 32 uints (128 fp8)
  for (int i = tid; i < 64 * 32; i += 256) {
    int r = i >> 5, cc = i & 31;
    int gr = rowbase + r;
    if (gr < NT_N) {
      unsigned int u0 = *(unsigned int*)(As + r * LD1 + cc * 4);
      unsigned int u1 = *(unsigned int*)(As + r * LD1 + cc * 4 + 2);
      int p = 0;
      p = __builtin_amdgcn_cvt_pk_fp8_f32(bflo(u0) * PQ_SCALE, bfhi(u0) * PQ_SCALE, p, false);
      p = __builtin_amdgcn_cvt_pk_fp8_f32(bflo(u1) * PQ_SCALE, bfhi(u1) * PQ_SCALE, p, true);
      dst[(size_t)gr * 32 + cc] = (unsigned int)p;
    }
  }
}

// ---------------- K1: fp8 gather-relu-reduce + softmax -> E ------------------
// R13: row = 128 fp8 = 8 lanes x uint4 (16 cols each); 32 (wave,slot) groups
// x 2 row-iters cover the 64 nodes. 18 gathered dwordx4 loads per thread
// (was 36 dwordx2). Reduction over 32 partials (was 16).
__global__ __launch_bounds__(256)
void k1_gather(const int* __restrict__ node_type, const int* __restrict__ nbr_type,
               const uint4* __restrict__ P8, const uint4* __restrict__ Q8,
               float* __restrict__ E)
{
  __shared__ int nts[64];
  __shared__ int nbs[512];
  __shared__ float rg[32][132];
  __shared__ float pg[128];

  const int g    = blockIdx.x;
  const int tid  = threadIdx.x;
  const int wave = tid >> 6, lane = tid & 63;
  const int slot = lane >> 3, cl = lane & 7;   // 8 slots x 8 lanes; 16 cols/lane

  if (tid < 64) nts[tid] = node_type[g * K_N + tid];
  nbs[tid]       = nbr_type[(size_t)g * 512 + tid];
  nbs[256 + tid] = nbr_type[(size_t)g * 512 + 256 + tid];
  __syncthreads();

  const int grp = wave * 8 + slot;             // [0,32)
  float acc[16];
  #pragma unroll
  for (int i = 0; i < 16; ++i) acc[i] = 0.f;

  #pragma unroll
  for (int it = 0; it < 2; ++it) {
    const int r = it * 32 + grp;
    float rv[16];
    fp8x16_to_f32(P8[(size_t)nts[r] * 8 + cl], rv);
    const int* nb = nbs + r * DEG_INN;
    #pragma unroll
    for (int d = 0; d < DEG_INN; ++d)
      fp8x16_acc(Q8[(size_t)nb[d] * 8 + cl], rv);
    #pragma unroll
    for (int i = 0; i < 16; ++i) acc[i] += fmaxf(rv[i], 0.f);
  }

  #pragma unroll
  for (int i = 0; i < 16; ++i) rg[grp][cl * 16 + i] = acc[i];
  __syncthreads();

  if (tid < 128) {
    float s = 0.f;
    #pragma unroll
    for (int q = 0; q < 32; ++q) s += rg[q][tid];
    pg[tid] = s;
  }
  __syncthreads();

  if (wave == 0) {
    float v0 = pg[lane] * PQ_INV, v1 = pg[64 + lane] * PQ_INV;  // undo fp8 scale
    float mx = fmaxf(v0, v1);
    #pragma unroll
    for (int o = 32; o; o >>= 1) mx = fmaxf(mx, __shfl_xor(mx, o, 64));
    float e0 = __expf(v0 - mx), e1 = __expf(v1 - mx);
    float s = e0 + e1;
    #pragma unroll
    for (int o = 32; o; o >>= 1) s += __shfl_xor(s, o, 64);
    float inv = 1.f / s;
    E[(size_t)g * D + lane]      = e0 * inv;
    E[(size_t)g * D + 64 + lane] = e1 * inv;
  }
}

// ---------------- K3: ext = E@U^T + Esum@V^T ; X = softmax(relu(ext)) --------
// 1 graph/block (2000 blocks). R12: weight inner loop reads uint4 (dwordx4,
// 16 B/lane covering k..k+3) from the k-interleaved Ut/Vt layout.
__global__ __launch_bounds__(256)
void k3_ext(const int* __restrict__ ext_nbr, const float* __restrict__ E,
            const unsigned int* __restrict__ Ut, const unsigned int* __restrict__ Vt,
            float* __restrict__ X)
{
  __shared__ float Ev[128], Es[128];
  __shared__ float p0[4][64], p1[4][64];
  __shared__ int en[16];

  const int g   = blockIdx.x;
  const int tid = threadIdx.x;
  const int jc  = tid & 63, grp = tid >> 6;
  const int lane = tid & 63, wave = tid >> 6;

  if (tid < 16) en[tid] = ext_nbr[g * DEG_EXTN + tid];
  __syncthreads();

  if (tid < 128) {
    Ev[tid] = E[(size_t)g * D + tid];
  } else {
    const int j = tid - 128;
    float a = 0.f;
    #pragma unroll
    for (int d = 0; d < DEG_EXTN; ++d) a += E[(size_t)en[d] * D + j];
    Es[j] = a;
  }
  __syncthreads();

  const uint4* T   = (grp & 2) ? (const uint4*)Vt : (const uint4*)Ut;
  const float* act = (grp & 2) ? Es : Ev;
  const int kb = (grp & 1) * 16;          // uint4-group base (64 k / 4)
  const float* ab = act + (grp & 1) * 64;
  float s0 = 0.f, s1 = 0.f;
  #pragma unroll
  for (int kk = 0; kk < 16; ++kk) {
    uint4 w = T[(kb + kk) * 64 + jc];
    const float* a = ab + kk * 4;
    s0 += bflo(w.x) * a[0] + bflo(w.y) * a[1] + bflo(w.z) * a[2] + bflo(w.w) * a[3];
    s1 += bfhi(w.x) * a[0] + bfhi(w.y) * a[1] + bfhi(w.z) * a[2] + bfhi(w.w) * a[3];
  }
  p0[grp][jc] = s0; p1[grp][jc] = s1;
  __syncthreads();

  // wave 0: cols lane and lane+64; col c -> p{c&1}[grp][c>>1] summed over grp
  if (wave == 0) {
    const int jc2 = lane >> 1;
    const bool hi = lane & 1;
    float va = hi ? (p1[0][jc2] + p1[1][jc2] + p1[2][jc2] + p1[3][jc2])
                  : (p0[0][jc2] + p0[1][jc2] + p0[2][jc2] + p0[3][jc2]);
    float vb = hi ? (p1[0][32 + jc2] + p1[1][32 + jc2] + p1[2][32 + jc2] + p1[3][32 + jc2])
                  : (p0[0][32 + jc2] + p0[1][32 + jc2] + p0[2][32 + jc2] + p0[3][32 + jc2]);
    float r0 = fmaxf(va, 0.f), r1 = fmaxf(vb, 0.f);
    float mx = fmaxf(r0, r1);
    #pragma unroll
    for (int o = 32; o; o >>= 1) mx = fmaxf(mx, __shfl_xor(mx, o, 64));
    float e0 = __expf(r0 - mx), e1 = __expf(r1 - mx);
    float sm = e0 + e1;
    #pragma unroll
    for (int o = 32; o; o >>= 1) sm += __shfl_xor(sm, o, 64);
    float inv = 1.f / sm;
    X[(size_t)g * D + lane]      = e0 * inv;
    X[(size_t)g * D + 64 + lane] = e1 * inv;
  }
}

// ---------------- K4: final MLP + 2-way softmax ------------------------------
// 1 item/block (1024 blocks). R12: W1t inner loop reads uint4 like k3.
__global__ __launch_bounds__(256)
void k4_mlp(const int* __restrict__ batch, const float* __restrict__ Xv,
            const unsigned int* __restrict__ W1t, const float* __restrict__ b1,
            const float* __restrict__ W2, const float* __restrict__ b2,
            float* __restrict__ out)
{
  __shared__ float feat[256];
  __shared__ float q0[4][64], q1[4][64];

  const int tid = threadIdx.x;
  const int jc = tid & 63, grp = tid >> 6;
  const int lane = tid & 63, wave = tid >> 6;

  const int b = blockIdx.x;
  const int i1 = batch[2 * b], i2 = batch[2 * b + 1];
  if (tid < 128) {
    float e1 = Xv[(size_t)i1 * D + tid], e2 = Xv[(size_t)i2 * D + tid];
    feat[tid]       = e1 * e2;
    feat[128 + tid] = e1 + e2;
  }
  __syncthreads();

  const uint4* W1t4 = (const uint4*)W1t;
  float s0 = 0.f, s1 = 0.f;
  #pragma unroll
  for (int kk = 0; kk < 16; ++kk) {
    uint4 w = W1t4[(grp * 16 + kk) * 64 + jc];
    const float* a = feat + grp * 64 + kk * 4;
    s0 += bflo(w.x) * a[0] + bflo(w.y) * a[1] + bflo(w.z) * a[2] + bflo(w.w) * a[3];
    s1 += bfhi(w.x) * a[0] + bfhi(w.y) * a[1] + bfhi(w.z) * a[2] + bfhi(w.w) * a[3];
  }
  q0[grp][jc] = s0; q1[grp][jc] = s1;
  __syncthreads();

  // wave 0: h for cols lane and lane+64, then both W2 dots via butterfly
  if (wave == 0) {
    const int jc2 = lane >> 1;
    const bool hi = lane & 1;
    float ha = hi ? (q1[0][jc2] + q1[1][jc2] + q1[2][jc2] + q1[3][jc2])
                  : (q0[0][jc2] + q0[1][jc2] + q0[2][jc2] + q0[3][jc2]);
    float hb = hi ? (q1[0][32 + jc2] + q1[1][32 + jc2] + q1[2][32 + jc2] + q1[3][32 + jc2])
                  : (q0[0][32 + jc2] + q0[1][32 + jc2] + q0[2][32 + jc2] + q0[3][32 + jc2]);
    float h0 = fmaxf(ha + b1[lane], 0.f);
    float h1 = fmaxf(hb + b1[64 + lane], 0.f);
    float t0 = W2[lane] * h0 + W2[64 + lane] * h1;
    float t1 = W2[128 + lane] * h0 + W2[192 + lane] * h1;
    #pragma unroll
    for (int o = 32; o; o >>= 1) {
      t0 += __shfl_xor(t0, o, 64);
      t1 += __shfl_xor(t1, o, 64);
    }
    if (lane == 0) {
      float r0 = t0 + b2[0], r1 = t1 + b2[1];
      float m = fmaxf(r0, r1);
      float e0 = __expf(r0 - m), e1 = __expf(r1 - m);
      float inv = 1.f / (e0 + e1);
      out[2 * b]     = e0 * inv;
      out[2 * b + 1] = e1 * inv;
    }
  }
}

// ---------------- launch -----------------------------------------------------
extern "C" void kernel_launch(void* const* d_in, const int* in_sizes, int n_in,
                              void* d_out, int out_size, void* d_ws, size_t ws_size,
                              hipStream_t stream) {
  const int* batch     = (const int*)d_in[0];
  const int* node_type = (const int*)d_in[1];
  const int* nbr_type  = (const int*)d_in[2];
  const int* ext_nbr   = (const int*)d_in[3];
  const float* impact  = (const float*)d_in[4];
  const float* W       = (const float*)d_in[5];
  const float* M       = (const float*)d_in[6];
  const float* U       = (const float*)d_in[7];
  const float* V       = (const float*)d_in[8];
  const float* W1      = (const float*)d_in[9];
  const float* b1      = (const float*)d_in[10];
  const float* W2      = (const float*)d_in[11];
  const float* b2      = (const float*)d_in[12];
  float* out           = (float*)d_out;

  float* E = (float*)d_ws;                                  // 2000*128 f32
  float* X = E + (size_t)G_N * D;                           // 2000*128 f32
  unsigned int* P8  = (unsigned int*)(X + (size_t)G_N * D); // 10000*32 uints (fp8 x4)
  unsigned int* Q8  = P8 + (size_t)NT_N * 32;               // 10000*32
  unsigned int* Ut  = Q8 + (size_t)NT_N * 32;               // 8192 (uint4-interleaved)
  unsigned int* Vt  = Ut + 8192;                            // 8192 (uint4-interleaved)
  unsigned int* W1t = Vt + 8192;                            // 16384 (uint4-interleaved)

  k0_prep<<<dim3((NT_N + 63) / 64, 3), 256, 0, stream>>>(impact, W, M, U, V, W1,
                                                         P8, Q8, Ut, Vt, W1t);
  k1_gather<<<G_N, 256, 0, stream>>>(node_type, nbr_type,
                                     (const uint4*)P8, (const uint4*)Q8, E);
  k3_ext<<<G_N, 256, 0, stream>>>(ext_nbr, E, Ut, Vt, X);
  k4_mlp<<<B_N, 256, 0, stream>>>(batch, X, W1t, b1, W2, b2, out);
}

// Round 4
// 116.717 us; speedup vs baseline: 1.0186x; 1.0186x over previous
//
#include <hip/hip_runtime.h>

typedef __bf16 bf16x8 __attribute__((ext_vector_type(8)));
typedef float f32x4 __attribute__((ext_vector_type(4)));
typedef float f32x2 __attribute__((ext_vector_type(2)));

#define G_N 2000
#define K_N 64
#define DEG_INN 8
#define DEG_EXTN 16
#define B_N 1024
#define D 128
#define NT_N 10000

// fp8 scale for P/Q tables (values ~N(0,0.014^2); x256 puts them mid e4m3 range)
#define PQ_SCALE 256.0f
#define PQ_INV   (1.0f / 256.0f)

__device__ __forceinline__ float bflo(unsigned int u) { return __uint_as_float(u << 16); }
__device__ __forceinline__ float bfhi(unsigned int u) { return __uint_as_float(u & 0xffff0000u); }
__device__ __forceinline__ unsigned short f2bf(float f) {
  unsigned int u = __float_as_uint(f);
  u += 0x7fffu + ((u >> 16) & 1u);
  return (unsigned short)(u >> 16);
}
__device__ __forceinline__ unsigned int pack2bf(float lo, float hi) {
  return ((unsigned int)f2bf(hi) << 16) | (unsigned int)f2bf(lo);
}

// ---------------- K0: P=impact@W^T, Q=impact@M^T (fp8 e4m3 x256) + transposes
// grid (157,3): y=0 -> P, y=1 -> Q, y=2 (x<16) -> Ut/Vt/W1t tile transposes.
// NOTE (R6): fusing y=0/y=1 into one block REGRESSED (latency/occupancy-bound).
// NOTE (R10): k1 shfl-slot-reduction + bf16 E regressed.
// NOTE (R11): cooperative k1+k3+k4 fusion REGRESSED 119->594 us; grid.sync()
// at 2000 blocks costs ~250 us/sync on gfx950. Never retry.
// R12 WIN: Ut/Vt/W1t k-interleaved-by-4, k3/k4 read uint4 -> 116.7 us.
// R13 REGRESSED (+2.2): k1 uint4 gathers -- gathered rows touch the same
// number of 128B segments regardless of per-lane width; VGPR/LDS grew. k1 must
// stay uint2/16-lane. Reverted here.
// R14 (this round): y=2 transpose was column-strided 4B loads (64 lines per
// wave instr, ~1 wave/CU). Now: 16 blocks, coalesced 64x64 f32 tile -> LDS
// ([64][68] pad, conflict-free both phases, overlaid on Bs) -> packed emit.
constexpr int LD1 = 136;

__global__ __launch_bounds__(256)
void k0_prep(const float* __restrict__ impact,
             const float* __restrict__ Wm, const float* __restrict__ Mm,
             const float* __restrict__ U, const float* __restrict__ V,
             const float* __restrict__ W1,
             unsigned int* __restrict__ P8, unsigned int* __restrict__ Q8,
             unsigned int* __restrict__ Ut, unsigned int* __restrict__ Vt,
             unsigned int* __restrict__ W1t)
{
  __shared__ __align__(16) unsigned short Bs[128 * LD1];
  __shared__ __align__(16) unsigned short As[64 * LD1];

  const int tid = threadIdx.x;

  if (blockIdx.y == 2) {
    if (blockIdx.x >= 16) return;
    // coalesced tile transpose: src 64x64 f32 tile -> k-interleaved bf16 pairs
    float (*tile)[68] = (float (*)[68])Bs;     // 64*68*4 = 17.4 KB <= Bs 34.8 KB
    const int t = blockIdx.x;
    const float* src; unsigned int* dst2; int srcld, r0, c0;
    if (t < 4)      { src = U;  dst2 = Ut;  srcld = D;   r0 = (t & 1) * 64;       c0 = (t >> 1) * 64; }
    else if (t < 8) { src = V;  dst2 = Vt;  srcld = D;   r0 = ((t - 4) & 1) * 64; c0 = ((t - 4) >> 1) * 64; }
    else            { src = W1; dst2 = W1t; srcld = 256; r0 = ((t - 8) & 1) * 64; c0 = ((t - 8) >> 1) * 64; }
    const int lrow = tid >> 4, lc4 = (tid & 15) * 4;
    #pragma unroll
    for (int it = 0; it < 4; ++it) {
      int row = it * 16 + lrow;
      float4 v = *(const float4*)(src + (size_t)(r0 + row) * srcld + c0 + lc4);
      tile[row][lc4]     = v.x; tile[row][lc4 + 1] = v.y;
      tile[row][lc4 + 2] = v.z; tile[row][lc4 + 3] = v.w;
    }
    __syncthreads();
    const int kp = tid & 63, jp = tid >> 6;
    #pragma unroll
    for (int it = 0; it < 8; ++it) {
      int jcl = it * 4 + jp;                    // local row-pair [0,32)
      int jc  = (r0 >> 1) + jcl;
      int k   = c0 + kp;
      dst2[(k >> 2) * 256 + jc * 4 + (k & 3)] =
          pack2bf(tile[2 * jcl][kp], tile[2 * jcl + 1][kp]);
    }
    return;
  }

  const int rowbase = blockIdx.x * 64;
  const float* Bsrc = blockIdx.y ? Mm : Wm;
  unsigned int* dst = blockIdx.y ? Q8 : P8;
  const int wave = tid >> 6, lane = tid & 63;

  for (int i = tid; i < 128 * 32; i += 256) {
    int row = i >> 5, c4 = i & 31;
    float4 v = ((const float4*)Bsrc)[row * 32 + c4];
    *(unsigned int*)(Bs + row * LD1 + c4 * 4)     = pack2bf(v.x, v.y);
    *(unsigned int*)(Bs + row * LD1 + c4 * 4 + 2) = pack2bf(v.z, v.w);
  }
  for (int i = tid; i < 64 * 32; i += 256) {
    int r = i >> 5, c4 = i & 31;
    int gr = rowbase + r; if (gr > NT_N - 1) gr = NT_N - 1;
    float4 v = ((const float4*)impact)[(size_t)gr * 32 + c4];
    *(unsigned int*)(As + r * LD1 + c4 * 4)     = pack2bf(v.x, v.y);
    *(unsigned int*)(As + r * LD1 + c4 * 4 + 2) = pack2bf(v.z, v.w);
  }
  __syncthreads();

  f32x4 acc[8];
  #pragma unroll
  for (int n = 0; n < 8; ++n) acc[n] = (f32x4){0.f, 0.f, 0.f, 0.f};
  const int qk   = (lane >> 4) * 8;
  const int arow = wave * 16 + (lane & 15);
  #pragma unroll
  for (int kk = 0; kk < 4; ++kk) {
    bf16x8 af = *(const bf16x8*)(As + arow * LD1 + kk * 32 + qk);
    #pragma unroll
    for (int n = 0; n < 8; ++n) {
      bf16x8 bfr = *(const bf16x8*)(Bs + (n * 16 + (lane & 15)) * LD1 + kk * 32 + qk);
      acc[n] = __builtin_amdgcn_mfma_f32_16x16x32_bf16(af, bfr, acc[n], 0, 0, 0);
    }
  }
  __syncthreads();

  // repack C (col=lane&15, row=(lane>>4)*4+reg) into As as bf16 rows
  const int quad = lane >> 4, c = lane & 15;
  #pragma unroll
  for (int n = 0; n < 8; ++n)
    #pragma unroll
    for (int reg = 0; reg < 4; ++reg)
      As[(wave * 16 + quad * 4 + reg) * LD1 + n * 16 + c] = f2bf(acc[n][reg]);
  __syncthreads();

  // write fp8 e4m3 (x256): row = 32 uints (128 fp8)
  for (int i = tid; i < 64 * 32; i += 256) {
    int r = i >> 5, cc = i & 31;
    int gr = rowbase + r;
    if (gr < NT_N) {
      unsigned int u0 = *(unsigned int*)(As + r * LD1 + cc * 4);
      unsigned int u1 = *(unsigned int*)(As + r * LD1 + cc * 4 + 2);
      int p = 0;
      p = __builtin_amdgcn_cvt_pk_fp8_f32(bflo(u0) * PQ_SCALE, bfhi(u0) * PQ_SCALE, p, false);
      p = __builtin_amdgcn_cvt_pk_fp8_f32(bflo(u1) * PQ_SCALE, bfhi(u1) * PQ_SCALE, p, true);
      dst[(size_t)gr * 32 + cc] = (unsigned int)p;
    }
  }
}

// ---------------- K1: fp8 gather-relu-reduce + softmax -> E ------------------
// Row = 128 fp8 = 16 lanes x uint2 (8 cols each). Body = R9/R12 form (R13's
// uint4 variant regressed; gathered rows don't benefit from wider lanes).
__global__ __launch_bounds__(256)
void k1_gather(const int* __restrict__ node_type, const int* __restrict__ nbr_type,
               const uint2* __restrict__ P8, const uint2* __restrict__ Q8,
               float* __restrict__ E)
{
  __shared__ int nts[64];
  __shared__ int nbs[512];
  __shared__ float rg[16][132];
  __shared__ float pg[128];

  const int g    = blockIdx.x;
  const int tid  = threadIdx.x;
  const int wave = tid >> 6, lane = tid & 63;
  const int slot = lane >> 4, cl = lane & 15;

  if (tid < 64) nts[tid] = node_type[g * K_N + tid];
  nbs[tid]       = nbr_type[(size_t)g * 512 + tid];
  nbs[256 + tid] = nbr_type[(size_t)g * 512 + 256 + tid];
  __syncthreads();

  float acc[8];
  #pragma unroll
  for (int i = 0; i < 8; ++i) acc[i] = 0.f;

  for (int it = 0; it < 4; ++it) {
    const int r = wave * 16 + it * 4 + slot;
    uint2 sv = P8[(size_t)nts[r] * 16 + cl];
    f32x2 a01 = __builtin_amdgcn_cvt_pk_f32_fp8(sv.x, false);
    f32x2 a23 = __builtin_amdgcn_cvt_pk_f32_fp8(sv.x, true);
    f32x2 a45 = __builtin_amdgcn_cvt_pk_f32_fp8(sv.y, false);
    f32x2 a67 = __builtin_amdgcn_cvt_pk_f32_fp8(sv.y, true);
    float rv[8] = {a01[0], a01[1], a23[0], a23[1], a45[0], a45[1], a67[0], a67[1]};
    const int* nb = nbs + r * DEG_INN;
    #pragma unroll
    for (int d = 0; d < DEG_INN; ++d) {
      uint2 qv = Q8[(size_t)nb[d] * 16 + cl];
      f32x2 b01 = __builtin_amdgcn_cvt_pk_f32_fp8(qv.x, false);
      f32x2 b23 = __builtin_amdgcn_cvt_pk_f32_fp8(qv.x, true);
      f32x2 b45 = __builtin_amdgcn_cvt_pk_f32_fp8(qv.y, false);
      f32x2 b67 = __builtin_amdgcn_cvt_pk_f32_fp8(qv.y, true);
      rv[0] += b01[0]; rv[1] += b01[1]; rv[2] += b23[0]; rv[3] += b23[1];
      rv[4] += b45[0]; rv[5] += b45[1]; rv[6] += b67[0]; rv[7] += b67[1];
    }
    #pragma unroll
    for (int i = 0; i < 8; ++i) acc[i] += fmaxf(rv[i], 0.f);
  }

  const int grp = wave * 4 + slot;
  #pragma unroll
  for (int i = 0; i < 8; ++i) rg[grp][cl * 8 + i] = acc[i];
  __syncthreads();

  if (tid < 128) {
    float s = 0.f;
    #pragma unroll
    for (int q = 0; q < 16; ++q) s += rg[q][tid];
    pg[tid] = s;
  }
  __syncthreads();

  if (wave == 0) {
    float v0 = pg[lane] * PQ_INV, v1 = pg[64 + lane] * PQ_INV;  // undo fp8 scale
    float mx = fmaxf(v0, v1);
    #pragma unroll
    for (int o = 32; o; o >>= 1) mx = fmaxf(mx, __shfl_xor(mx, o, 64));
    float e0 = __expf(v0 - mx), e1 = __expf(v1 - mx);
    float s = e0 + e1;
    #pragma unroll
    for (int o = 32; o; o >>= 1) s += __shfl_xor(s, o, 64);
    float inv = 1.f / s;
    E[(size_t)g * D + lane]      = e0 * inv;
    E[(size_t)g * D + 64 + lane] = e1 * inv;
  }
}

// ---------------- K3: ext = E@U^T + Esum@V^T ; X = softmax(relu(ext)) --------
// 1 graph/block (2000 blocks). R12: weight inner loop reads uint4 (dwordx4,
// 16 B/lane covering k..k+3) from the k-interleaved Ut/Vt layout.
__global__ __launch_bounds__(256)
void k3_ext(const int* __restrict__ ext_nbr, const float* __restrict__ E,
            const unsigned int* __restrict__ Ut, const unsigned int* __restrict__ Vt,
            float* __restrict__ X)
{
  __shared__ float Ev[128], Es[128];
  __shared__ float p0[4][64], p1[4][64];
  __shared__ int en[16];

  const int g   = blockIdx.x;
  const int tid = threadIdx.x;
  const int jc  = tid & 63, grp = tid >> 6;
  const int lane = tid & 63, wave = tid >> 6;

  if (tid < 16) en[tid] = ext_nbr[g * DEG_EXTN + tid];
  __syncthreads();

  if (tid < 128) {
    Ev[tid] = E[(size_t)g * D + tid];
  } else {
    const int j = tid - 128;
    float a = 0.f;
    #pragma unroll
    for (int d = 0; d < DEG_EXTN; ++d) a += E[(size_t)en[d] * D + j];
    Es[j] = a;
  }
  __syncthreads();

  const uint4* T   = (grp & 2) ? (const uint4*)Vt : (const uint4*)Ut;
  const float* act = (grp & 2) ? Es : Ev;
  const int kb = (grp & 1) * 16;          // uint4-group base (64 k / 4)
  const float* ab = act + (grp & 1) * 64;
  float s0 = 0.f, s1 = 0.f;
  #pragma unroll
  for (int kk = 0; kk < 16; ++kk) {
    uint4 w = T[(kb + kk) * 64 + jc];
    const float* a = ab + kk * 4;
    s0 += bflo(w.x) * a[0] + bflo(w.y) * a[1] + bflo(w.z) * a[2] + bflo(w.w) * a[3];
    s1 += bfhi(w.x) * a[0] + bfhi(w.y) * a[1] + bfhi(w.z) * a[2] + bfhi(w.w) * a[3];
  }
  p0[grp][jc] = s0; p1[grp][jc] = s1;
  __syncthreads();

  // wave 0: cols lane and lane+64; col c -> p{c&1}[grp][c>>1] summed over grp
  if (wave == 0) {
    const int jc2 = lane >> 1;
    const bool hi = lane & 1;
    float va = hi ? (p1[0][jc2] + p1[1][jc2] + p1[2][jc2] + p1[3][jc2])
                  : (p0[0][jc2] + p0[1][jc2] + p0[2][jc2] + p0[3][jc2]);
    float vb = hi ? (p1[0][32 + jc2] + p1[1][32 + jc2] + p1[2][32 + jc2] + p1[3][32 + jc2])
                  : (p0[0][32 + jc2] + p0[1][32 + jc2] + p0[2][32 + jc2] + p0[3][32 + jc2]);
    float r0 = fmaxf(va, 0.f), r1 = fmaxf(vb, 0.f);
    float mx = fmaxf(r0, r1);
    #pragma unroll
    for (int o = 32; o; o >>= 1) mx = fmaxf(mx, __shfl_xor(mx, o, 64));
    float e0 = __expf(r0 - mx), e1 = __expf(r1 - mx);
    float sm = e0 + e1;
    #pragma unroll
    for (int o = 32; o; o >>= 1) sm += __shfl_xor(sm, o, 64);
    float inv = 1.f / sm;
    X[(size_t)g * D + lane]      = e0 * inv;
    X[(size_t)g * D + 64 + lane] = e1 * inv;
  }
}

// ---------------- K4: final MLP + 2-way softmax ------------------------------
// 1 item/block (1024 blocks). R12: W1t inner loop reads uint4 like k3.
__global__ __launch_bounds__(256)
void k4_mlp(const int* __restrict__ batch, const float* __restrict__ Xv,
            const unsigned int* __restrict__ W1t, const float* __restrict__ b1,
            const float* __restrict__ W2, const float* __restrict__ b2,
            float* __restrict__ out)
{
  __shared__ float feat[256];
  __shared__ float q0[4][64], q1[4][64];

  const int tid = threadIdx.x;
  const int jc = tid & 63, grp = tid >> 6;
  const int lane = tid & 63, wave = tid >> 6;

  const int b = blockIdx.x;
  const int i1 = batch[2 * b], i2 = batch[2 * b + 1];
  if (tid < 128) {
    float e1 = Xv[(size_t)i1 * D + tid], e2 = Xv[(size_t)i2 * D + tid];
    feat[tid]       = e1 * e2;
    feat[128 + tid] = e1 + e2;
  }
  __syncthreads();

  const uint4* W1t4 = (const uint4*)W1t;
  float s0 = 0.f, s1 = 0.f;
  #pragma unroll
  for (int kk = 0; kk < 16; ++kk) {
    uint4 w = W1t4[(grp * 16 + kk) * 64 + jc];
    const float* a = feat + grp * 64 + kk * 4;
    s0 += bflo(w.x) * a[0] + bflo(w.y) * a[1] + bflo(w.z) * a[2] + bflo(w.w) * a[3];
    s1 += bfhi(w.x) * a[0] + bfhi(w.y) * a[1] + bfhi(w.z) * a[2] + bfhi(w.w) * a[3];
  }
  q0[grp][jc] = s0; q1[grp][jc] = s1;
  __syncthreads();

  // wave 0: h for cols lane and lane+64, then both W2 dots via butterfly
  if (wave == 0) {
    const int jc2 = lane >> 1;
    const bool hi = lane & 1;
    float ha = hi ? (q1[0][jc2] + q1[1][jc2] + q1[2][jc2] + q1[3][jc2])
                  : (q0[0][jc2] + q0[1][jc2] + q0[2][jc2] + q0[3][jc2]);
    float hb = hi ? (q1[0][32 + jc2] + q1[1][32 + jc2] + q1[2][32 + jc2] + q1[3][32 + jc2])
                  : (q0[0][32 + jc2] + q0[1][32 + jc2] + q0[2][32 + jc2] + q0[3][32 + jc2]);
    float h0 = fmaxf(ha + b1[lane], 0.f);
    float h1 = fmaxf(hb + b1[64 + lane], 0.f);
    float t0 = W2[lane] * h0 + W2[64 + lane] * h1;
    float t1 = W2[128 + lane] * h0 + W2[192 + lane] * h1;
    #pragma unroll
    for (int o = 32; o; o >>= 1) {
      t0 += __shfl_xor(t0, o, 64);
      t1 += __shfl_xor(t1, o, 64);
    }
    if (lane == 0) {
      float r0 = t0 + b2[0], r1 = t1 + b2[1];
      float m = fmaxf(r0, r1);
      float e0 = __expf(r0 - m), e1 = __expf(r1 - m);
      float inv = 1.f / (e0 + e1);
      out[2 * b]     = e0 * inv;
      out[2 * b + 1] = e1 * inv;
    }
  }
}

// ---------------- launch -----------------------------------------------------
extern "C" void kernel_launch(void* const* d_in, const int* in_sizes, int n_in,
                              void* d_out, int out_size, void* d_ws, size_t ws_size,
                              hipStream_t stream) {
  const int* batch     = (const int*)d_in[0];
  const int* node_type = (const int*)d_in[1];
  const int* nbr_type  = (const int*)d_in[2];
  const int* ext_nbr   = (const int*)d_in[3];
  const float* impact  = (const float*)d_in[4];
  const float* W       = (const float*)d_in[5];
  const float* M       = (const float*)d_in[6];
  const float* U       = (const float*)d_in[7];
  const float* V       = (const float*)d_in[8];
  const float* W1      = (const float*)d_in[9];
  const float* b1      = (const float*)d_in[10];
  const float* W2      = (const float*)d_in[11];
  const float* b2      = (const float*)d_in[12];
  float* out           = (float*)d_out;

  float* E = (float*)d_ws;                                  // 2000*128 f32
  float* X = E + (size_t)G_N * D;                           // 2000*128 f32
  unsigned int* P8  = (unsigned int*)(X + (size_t)G_N * D); // 10000*32 uints (fp8 x4)
  unsigned int* Q8  = P8 + (size_t)NT_N * 32;               // 10000*32
  unsigned int* Ut  = Q8 + (size_t)NT_N * 32;               // 8192 (uint4-interleaved)
  unsigned int* Vt  = Ut + 8192;                            // 8192 (uint4-interleaved)
  unsigned int* W1t = Vt + 8192;                            // 16384 (uint4-interleaved)

  k0_prep<<<dim3((NT_N + 63) / 64, 3), 256, 0, stream>>>(impact, W, M, U, V, W1,
                                                         P8, Q8, Ut, Vt, W1t);
  k1_gather<<<G_N, 256, 0, stream>>>(node_type, nbr_type,
                                     (const uint2*)P8, (const uint2*)Q8, E);
  k3_ext<<<G_N, 256, 0, stream>>>(ext_nbr, E, Ut, Vt, X);
  k4_mlp<<<B_N, 256, 0, stream>>>(batch, X, W1t, b1, W2, b2, out);
}